// Round 9
// baseline (695.379 us; speedup 1.0000x reference)
//
#include <hip/hip_runtime.h>
#include <math.h>

#define NB 16
#define NL 4096
#define ND 192
#define NH 384
#define NS 16
#define NTK 17
#define NIR 128
#define NR 24
#define NHH 64
#define NWW 64
#define NCHUNKS 32
#define CHUNKLEN 128
#define NTOK (NB*NL)

typedef __attribute__((ext_vector_type(8))) short short8;
typedef __attribute__((ext_vector_type(4))) float floatx4;

__device__ __forceinline__ float gelu_tanh(float x){
  return 0.5f*x*(1.0f + tanhf(0.7978845608028654f*(x + 0.044715f*x*x*x)));
}
__device__ __forceinline__ float softplus_f(float x){
  return (x > 20.0f) ? x : log1pf(expf(x));
}
__device__ __forceinline__ short f2bf(float f){
  unsigned u = __float_as_uint(f);
  unsigned r = (u + 0x7fffu + ((u >> 16) & 1u)) >> 16;
  return (short)r;
}

union Pack8 { uint4 v; short s[8]; };

// Merged pre-pass: blocks 0..63 = weights->bf16 (+ full_emb on block 0);
// blocks 64..1087 = routing MLP + argmax (independent work, one launch saved).
__global__ __launch_bounds__(256) void k_pre(
    const float* __restrict__ inw, const float* __restrict__ ow,
    const float* __restrict__ xpw, const float* __restrict__ dtw,
    short* __restrict__ inwb, short* __restrict__ owb,
    short* __restrict__ xpwb, short* __restrict__ dtwb,
    const float* __restrict__ embB, const float* __restrict__ tw,
    float* __restrict__ fe,
    const float* __restrict__ x, const float* __restrict__ rw1,
    const float* __restrict__ rb1, const float* __restrict__ rw2,
    const float* __restrict__ rb2, const float* __restrict__ gumbel,
    int* __restrict__ idx){
  __shared__ float As[16][68];
  __shared__ float Ws[16][68];
  __shared__ float hm[64*65];
  __shared__ float w2s[NTK*64];
  int tid = threadIdx.x;
  int bl = blockIdx.x;
  if (bl < 64){
    // ---- weight conversion path (stride = 64 blocks, as in old k_cvtw) ----
    int i = bl*256 + tid;
    int stride = 64*256;
    for (int p = i; p < NH*ND; p += stride) inwb[p] = f2bf(inw[p]);
    for (int p = i; p < ND*NH; p += stride) owb[p] = f2bf(ow[p]);
    for (int p = i; p < 56*NH; p += stride) xpwb[p] = f2bf(xpw[p]);
    for (int p = i; p < NH*32; p += stride){
      int r = p >> 5, c = p & 31;
      dtwb[p] = (c < NR) ? f2bf(dtw[r*NR + c]) : (short)0;
    }
    if (bl == 0){
      for (int o = tid; o < NTK*NS; o += 256){
        int t = o / NS, s = o % NS;
        float acc = 0.f;
        for (int k = 0; k < NIR; ++k) acc += embB[t*NIR+k]*tw[k*NS+s];
        fe[o] = acc;
      }
    }
    return;
  }
  // ---- routing path: hmid = gelu(x@rw1^T+rb1); idx = argmax(...) ----
  int m0 = (bl - 64)*64;
  int tx = tid & 15, ty = tid >> 4;
  int srow = tid >> 2, skseg = (tid & 3)*4;
  for (int p = tid; p < NTK*64; p += 256) w2s[p] = rw2[p];
  float acc[4][4] = {};
  for (int k0 = 0; k0 < ND; k0 += 16){
    {
      const float* ap = x + (size_t)(m0+srow)*ND + k0 + skseg;
      float4 v = *(const float4*)ap;
      As[skseg+0][srow]=v.x; As[skseg+1][srow]=v.y;
      As[skseg+2][srow]=v.z; As[skseg+3][srow]=v.w;
    }
    {
      float4 v = *(const float4*)(rw1 + (size_t)srow*ND + k0 + skseg);
      Ws[skseg+0][srow]=v.x; Ws[skseg+1][srow]=v.y;
      Ws[skseg+2][srow]=v.z; Ws[skseg+3][srow]=v.w;
    }
    __syncthreads();
    #pragma unroll
    for (int kk = 0; kk < 16; ++kk){
      float4 av = *(const float4*)&As[kk][ty*4];
      float4 wv = *(const float4*)&Ws[kk][tx*4];
      acc[0][0] += av.x*wv.x; acc[0][1] += av.x*wv.y;
      acc[0][2] += av.x*wv.z; acc[0][3] += av.x*wv.w;
      acc[1][0] += av.y*wv.x; acc[1][1] += av.y*wv.y;
      acc[1][2] += av.y*wv.z; acc[1][3] += av.y*wv.w;
      acc[2][0] += av.z*wv.x; acc[2][1] += av.z*wv.y;
      acc[2][2] += av.z*wv.z; acc[2][3] += av.z*wv.w;
      acc[3][0] += av.w*wv.x; acc[3][1] += av.w*wv.y;
      acc[3][2] += av.w*wv.z; acc[3][3] += av.w*wv.w;
    }
    __syncthreads();
  }
  #pragma unroll
  for (int i = 0; i < 4; ++i)
    #pragma unroll
    for (int j = 0; j < 4; ++j)
      hm[(ty*4+i)*65 + tx*4+j] = gelu_tanh(acc[i][j] + rb1[tx*4+j]);
  __syncthreads();
  if (tid < 64){
    int g = m0 + tid;
    const float* hr = &hm[tid*65];
    float best = -INFINITY; int bi = 0;
    for (int c = 0; c < NTK; ++c){
      float s = rb2[c] + gumbel[(size_t)g*NTK + c];
      #pragma unroll
      for (int j = 0; j < 64; ++j) s += hr[j]*w2s[c*64+j];
      if (s > best){ best = s; bi = c; }
    }
    idx[g] = bi;
  }
}

// bf16 MFMA GEMM: C(MxN) = A(MxK) @ W(NxK bf16)^T + bias.
// A fp32 (AF32=1, converted during LDS staging) or bf16 (AF32=0).
// LNA=1: apply per-row layernorm (mean/rstd precomputed; g/b over K) during staging.
// EPI: 0 none, 2 softplus, 3 row-scatter via remap
template<int EPI, int AF32, int LNA>
__global__ __launch_bounds__(256) void k_mfma(const void* __restrict__ Aptr, int lda,
    const short* __restrict__ Wbf, int ldw, const float* __restrict__ bias,
    float* __restrict__ C, int ldc, int N, int K, const int* __restrict__ remap,
    const float* __restrict__ lnm, const float* __restrict__ lnr,
    const float* __restrict__ lng, const float* __restrict__ lnb){
  __shared__ short As[128*40];   // stride 40 shorts = 80B: 16B-aligned b128, 2-way banks (free)
  __shared__ short Bs[64*40];
  int tid = threadIdx.x;
  int m0 = blockIdx.x*128, n0 = blockIdx.y*64;
  int w = tid >> 6, lane = tid & 63;
  int lq = lane >> 4, lr = lane & 15;
  floatx4 acc[2][4];
  #pragma unroll
  for (int i = 0; i < 2; ++i)
    #pragma unroll
    for (int j = 0; j < 4; ++j) acc[i][j] = (floatx4){0.f,0.f,0.f,0.f};
  int ar = tid >> 1, aq = (tid & 1)*2;   // A: each thread stages 16 elts of one row
  int br = tid >> 2, bq = tid & 3;       // B: each thread stages 8 elts of one row
  float mr = 0.f, rr = 0.f;
  if (LNA){ mr = lnm[m0+ar]; rr = lnr[m0+ar]; }
  for (int k0 = 0; k0 < K; k0 += 32){
    Pack8 sa0, sa1;
    if (AF32){
      const float* ap = (const float*)Aptr + (size_t)(m0+ar)*lda + k0 + aq*8;
      float f[16];
      float4 f0 = *(const float4*)(ap);
      float4 f1 = *(const float4*)(ap+4);
      float4 f2 = *(const float4*)(ap+8);
      float4 f3 = *(const float4*)(ap+12);
      f[0]=f0.x; f[1]=f0.y; f[2]=f0.z; f[3]=f0.w;
      f[4]=f1.x; f[5]=f1.y; f[6]=f1.z; f[7]=f1.w;
      f[8]=f2.x; f[9]=f2.y; f[10]=f2.z; f[11]=f2.w;
      f[12]=f3.x; f[13]=f3.y; f[14]=f3.z; f[15]=f3.w;
      if (LNA){
        const float* gp = lng + k0 + aq*8;
        const float* bp = lnb + k0 + aq*8;
        #pragma unroll
        for (int j = 0; j < 16; ++j) f[j] = (f[j]-mr)*rr*gp[j] + bp[j];
      }
      #pragma unroll
      for (int j = 0; j < 8; ++j){ sa0.s[j] = f2bf(f[j]); sa1.s[j] = f2bf(f[8+j]); }
    } else {
      const short* ap = (const short*)Aptr + (size_t)(m0+ar)*lda + k0 + aq*8;
      sa0.v = *(const uint4*)ap;
      sa1.v = *(const uint4*)(ap + 8);
    }
    uint4 bv = {0u,0u,0u,0u};
    if (n0 + br < N) bv = *(const uint4*)(Wbf + (size_t)(n0+br)*ldw + k0 + bq*8);
    __syncthreads();
    *(uint4*)&As[ar*40 + aq*8]     = sa0.v;
    *(uint4*)&As[ar*40 + aq*8 + 8] = sa1.v;
    *(uint4*)&Bs[br*40 + bq*8]     = bv;
    __syncthreads();
    short8 a0 = *(const short8*)&As[(w*32      + lr)*40 + lq*8];
    short8 a1 = *(const short8*)&As[(w*32 + 16 + lr)*40 + lq*8];
    short8 b0 = *(const short8*)&Bs[(     lr)*40 + lq*8];
    short8 b1 = *(const short8*)&Bs[(16 + lr)*40 + lq*8];
    short8 b2 = *(const short8*)&Bs[(32 + lr)*40 + lq*8];
    short8 b3 = *(const short8*)&Bs[(48 + lr)*40 + lq*8];
    acc[0][0] = __builtin_amdgcn_mfma_f32_16x16x32_bf16(a0, b0, acc[0][0], 0,0,0);
    acc[0][1] = __builtin_amdgcn_mfma_f32_16x16x32_bf16(a0, b1, acc[0][1], 0,0,0);
    acc[0][2] = __builtin_amdgcn_mfma_f32_16x16x32_bf16(a0, b2, acc[0][2], 0,0,0);
    acc[0][3] = __builtin_amdgcn_mfma_f32_16x16x32_bf16(a0, b3, acc[0][3], 0,0,0);
    acc[1][0] = __builtin_amdgcn_mfma_f32_16x16x32_bf16(a1, b0, acc[1][0], 0,0,0);
    acc[1][1] = __builtin_amdgcn_mfma_f32_16x16x32_bf16(a1, b1, acc[1][1], 0,0,0);
    acc[1][2] = __builtin_amdgcn_mfma_f32_16x16x32_bf16(a1, b2, acc[1][2], 0,0,0);
    acc[1][3] = __builtin_amdgcn_mfma_f32_16x16x32_bf16(a1, b3, acc[1][3], 0,0,0);
  }
  // C/D layout (verified m89): col = lane&15, row = (lane>>4)*4 + reg
  #pragma unroll
  for (int mt = 0; mt < 2; ++mt){
    #pragma unroll
    for (int r = 0; r < 4; ++r){
      int m = m0 + w*32 + mt*16 + lq*4 + r;
      int orow = (EPI==3) ? remap[m] : m;
      #pragma unroll
      for (int nt = 0; nt < 4; ++nt){
        int n = n0 + nt*16 + lr;
        if (n < N){
          float v = acc[mt][nt][r] + (bias ? bias[n] : 0.f);
          if (EPI==2) v = softplus_f(v);
          C[(size_t)orow*ldc + n] = v;
        }
      }
    }
  }
}

// x_dbl GEMM (N=56, K=384) with fused split epilogue AND fused delta-GEMM:
// cols 0..23 -> dts (bf16, kept in LDS, zero-pad 24..31), 24..39 -> Bsb,
// 40..55 -> Csb+prompt; then delta = softplus(dts @ dtw^T + dtb) for the
// block's own 128 rows (bit-identical to the old k_mfma<2,0,0> pass).
// Saves dtsb 8MB round-trip + one launch + 3072 block startups.
__global__ __launch_bounds__(256) void k_xdd(const float* __restrict__ us,
    const short* __restrict__ xpwb, const short* __restrict__ dtwb,
    const float* __restrict__ dtb, const int* __restrict__ idx,
    const float* __restrict__ fe, const int* __restrict__ gt,
    float* __restrict__ Bsb, float* __restrict__ Csb, float* __restrict__ delta){
  __shared__ short As[128*40];
  __shared__ short Bs[64*40];
  int tid = threadIdx.x;
  int m0 = blockIdx.x*128;
  int w = tid >> 6, lane = tid & 63;
  int lq = lane >> 4, lr = lane & 15;
  floatx4 acc[2][4];
  #pragma unroll
  for (int i = 0; i < 2; ++i)
    #pragma unroll
    for (int j = 0; j < 4; ++j) acc[i][j] = (floatx4){0.f,0.f,0.f,0.f};
  int ar = tid >> 1, aq = (tid & 1)*2;
  int br = tid >> 2, bq = tid & 3;
  for (int k0 = 0; k0 < NH; k0 += 32){
    Pack8 sa0, sa1;
    {
      const float* ap = us + (size_t)(m0+ar)*NH + k0 + aq*8;
      float f[16];
      float4 f0 = *(const float4*)(ap);
      float4 f1 = *(const float4*)(ap+4);
      float4 f2 = *(const float4*)(ap+8);
      float4 f3 = *(const float4*)(ap+12);
      f[0]=f0.x; f[1]=f0.y; f[2]=f0.z; f[3]=f0.w;
      f[4]=f1.x; f[5]=f1.y; f[6]=f1.z; f[7]=f1.w;
      f[8]=f2.x; f[9]=f2.y; f[10]=f2.z; f[11]=f2.w;
      f[12]=f3.x; f[13]=f3.y; f[14]=f3.z; f[15]=f3.w;
      #pragma unroll
      for (int j = 0; j < 8; ++j){ sa0.s[j] = f2bf(f[j]); sa1.s[j] = f2bf(f[8+j]); }
    }
    uint4 bv = {0u,0u,0u,0u};
    if (br < 56) bv = *(const uint4*)(xpwb + (size_t)br*NH + k0 + bq*8);
    __syncthreads();
    *(uint4*)&As[ar*40 + aq*8]     = sa0.v;
    *(uint4*)&As[ar*40 + aq*8 + 8] = sa1.v;
    *(uint4*)&Bs[br*40 + bq*8]     = bv;
    __syncthreads();
    short8 a0 = *(const short8*)&As[(w*32      + lr)*40 + lq*8];
    short8 a1 = *(const short8*)&As[(w*32 + 16 + lr)*40 + lq*8];
    short8 b0 = *(const short8*)&Bs[(     lr)*40 + lq*8];
    short8 b1 = *(const short8*)&Bs[(16 + lr)*40 + lq*8];
    short8 b2 = *(const short8*)&Bs[(32 + lr)*40 + lq*8];
    short8 b3 = *(const short8*)&Bs[(48 + lr)*40 + lq*8];
    acc[0][0] = __builtin_amdgcn_mfma_f32_16x16x32_bf16(a0, b0, acc[0][0], 0,0,0);
    acc[0][1] = __builtin_amdgcn_mfma_f32_16x16x32_bf16(a0, b1, acc[0][1], 0,0,0);
    acc[0][2] = __builtin_amdgcn_mfma_f32_16x16x32_bf16(a0, b2, acc[0][2], 0,0,0);
    acc[0][3] = __builtin_amdgcn_mfma_f32_16x16x32_bf16(a0, b3, acc[0][3], 0,0,0);
    acc[1][0] = __builtin_amdgcn_mfma_f32_16x16x32_bf16(a1, b0, acc[1][0], 0,0,0);
    acc[1][1] = __builtin_amdgcn_mfma_f32_16x16x32_bf16(a1, b1, acc[1][1], 0,0,0);
    acc[1][2] = __builtin_amdgcn_mfma_f32_16x16x32_bf16(a1, b2, acc[1][2], 0,0,0);
    acc[1][3] = __builtin_amdgcn_mfma_f32_16x16x32_bf16(a1, b3, acc[1][3], 0,0,0);
  }
  int gather = gt[0];
  __syncthreads();   // all K-loop LDS reads complete before As is overwritten
  // epilogue: Bsb/Csb to global; dts (cols 0..23) into As (bf16, stride 40)
  #pragma unroll
  for (int mt = 0; mt < 2; ++mt){
    #pragma unroll
    for (int r = 0; r < 4; ++r){
      int m = m0 + w*32 + mt*16 + lq*4 + r;
      int ml = m - m0;
      int id = idx[m];
      #pragma unroll
      for (int nt = 0; nt < 4; ++nt){
        int n = nt*16 + lr;
        float v = acc[mt][nt][r];
        if (n < 24){
          As[ml*40 + n] = f2bf(v);
        } else if (n < 40){
          Bsb[(size_t)m*NS + (n-24)] = v;
        } else if (n < 56){
          float cv = v;
          if (gather != 0) cv += fe[id*NS + (n-40)];
          Csb[(size_t)m*NS + (n-40)] = cv;
        }
      }
    }
  }
  if (tid < 128) *(uint4*)&As[tid*40 + 24] = (uint4){0u,0u,0u,0u};  // K pad 24..31
  __syncthreads();   // dts tile ready in As
  // delta-GEMM: M=128 (this block's rows), N=384 in 6 tiles of 64, K=32.
  short8 a0 = *(const short8*)&As[(w*32      + lr)*40 + lq*8];
  short8 a1 = *(const short8*)&As[(w*32 + 16 + lr)*40 + lq*8];
  for (int t6 = 0; t6 < 6; ++t6){
    if (t6) __syncthreads();          // previous tile's Bs reads done
    *(uint4*)&Bs[br*40 + bq*8] = *(const uint4*)(dtwb + (size_t)(t6*64+br)*32 + bq*8);
    __syncthreads();
    short8 b0 = *(const short8*)&Bs[(     lr)*40 + lq*8];
    short8 b1 = *(const short8*)&Bs[(16 + lr)*40 + lq*8];
    short8 b2 = *(const short8*)&Bs[(32 + lr)*40 + lq*8];
    short8 b3 = *(const short8*)&Bs[(48 + lr)*40 + lq*8];
    floatx4 d0[2][4];
    #pragma unroll
    for (int i = 0; i < 2; ++i)
      #pragma unroll
      for (int j = 0; j < 4; ++j) d0[i][j] = (floatx4){0.f,0.f,0.f,0.f};
    d0[0][0] = __builtin_amdgcn_mfma_f32_16x16x32_bf16(a0, b0, d0[0][0], 0,0,0);
    d0[0][1] = __builtin_amdgcn_mfma_f32_16x16x32_bf16(a0, b1, d0[0][1], 0,0,0);
    d0[0][2] = __builtin_amdgcn_mfma_f32_16x16x32_bf16(a0, b2, d0[0][2], 0,0,0);
    d0[0][3] = __builtin_amdgcn_mfma_f32_16x16x32_bf16(a0, b3, d0[0][3], 0,0,0);
    d0[1][0] = __builtin_amdgcn_mfma_f32_16x16x32_bf16(a1, b0, d0[1][0], 0,0,0);
    d0[1][1] = __builtin_amdgcn_mfma_f32_16x16x32_bf16(a1, b1, d0[1][1], 0,0,0);
    d0[1][2] = __builtin_amdgcn_mfma_f32_16x16x32_bf16(a1, b2, d0[1][2], 0,0,0);
    d0[1][3] = __builtin_amdgcn_mfma_f32_16x16x32_bf16(a1, b3, d0[1][3], 0,0,0);
    #pragma unroll
    for (int mt = 0; mt < 2; ++mt){
      #pragma unroll
      for (int r = 0; r < 4; ++r){
        int m = m0 + w*32 + mt*16 + lq*4 + r;
        #pragma unroll
        for (int nt = 0; nt < 4; ++nt){
          int n = t6*64 + nt*16 + lr;
          delta[(size_t)m*NH + n] = softplus_f(d0[mt][nt][r] + dtb[n]);
        }
      }
    }
  }
}

// stable counting sort per batch over 17 keys
__global__ __launch_bounds__(256) void k_sort(const int* __restrict__ idx,
    int* __restrict__ rmap, int* __restrict__ inv){
  int b = blockIdx.x, t = threadIdx.x;
  __shared__ int hist[NTK][256];
  __shared__ int tot[NTK];
  __shared__ int keybase[NTK];
  int keys[16];
  const int* ip = idx + b*NL + t*16;
  #pragma unroll
  for (int i = 0; i < 16; ++i) keys[i] = ip[i];
  #pragma unroll
  for (int k = 0; k < NTK; ++k){
    int c = 0;
    #pragma unroll
    for (int i = 0; i < 16; ++i) c += (keys[i]==k) ? 1 : 0;
    hist[k][t] = c;
  }
  __syncthreads();
  if (t < NTK){
    int run = 0;
    for (int j = 0; j < 256; ++j){ int v = hist[t][j]; hist[t][j] = run; run += v; }
    tot[t] = run;
  }
  __syncthreads();
  if (t == 0){
    int base = 0;
    for (int k = 0; k < NTK; ++k){ keybase[k] = base; base += tot[k]; }
  }
  __syncthreads();
  #pragma unroll
  for (int i = 0; i < 16; ++i){
    int k = keys[i];
    int cb = 0;
    #pragma unroll
    for (int j = 0; j < 16; ++j) cb += (j < i && keys[j]==k) ? 1 : 0;
    int pos = keybase[k] + hist[k][t] + cb;
    rmap[b*NL + pos] = b*NL + t*16 + i;
    inv[b*NL + t*16 + i] = pos;
  }
}

// depthwise 3x3 SAME conv + sigmoid gate; scatter rows to sorted order.
// Block (96,4): threadIdx.x IS the channel -> zero integer div/mod anywhere.
__global__ __launch_bounds__(384) void k_cpe(const float* __restrict__ xi,
    const float* __restrict__ cw, const float* __restrict__ cb,
    const int* __restrict__ inv, float* __restrict__ us){
  int bl = blockIdx.x;
  int cg = bl & 3;
  int xt = (bl>>2) & 7;
  int yt = (bl>>5) & 7;
  int b  = bl >> 8;
  __shared__ float tile[10*10*96];   // [yy][xx][c], c contiguous
  int tx = threadIdx.x;              // channel within group (0..95)
  int ty = threadIdx.y;              // spatial worker (0..3)
  int c0 = cg*96;
  int ch = c0 + tx;
  // stage 10x10 halo tile, c-major coalesced, no divisions
  for (int yy = 0; yy < 10; ++yy){
    int gy = yt*8 + yy - 1;
    for (int xx = ty; xx < 10; xx += 4){
      int gx = xt*8 + xx - 1;
      float v = 0.f;
      if (gy >= 0 && gy < NHH && gx >= 0 && gx < NWW)
        v = xi[((size_t)(b*NL + gy*NWW + gx))*NH + ch];
      tile[(yy*10 + xx)*96 + tx] = v;
    }
  }
  // conv weights fixed per thread: hoist to registers
  float wreg[9];
  #pragma unroll
  for (int j = 0; j < 9; ++j) wreg[j] = cw[ch*9 + j];
  float bias = cb[ch];
  __syncthreads();
  for (int yy = ty; yy < 8; yy += 4){
    #pragma unroll
    for (int xx = 0; xx < 8; ++xx){
      float acc = bias;
      #pragma unroll
      for (int dy = 0; dy < 3; ++dy)
        #pragma unroll
        for (int dx = 0; dx < 3; ++dx)
          acc += tile[((yy+dy)*10 + (xx+dx))*96 + tx] * wreg[dy*3+dx];
      float center = tile[((yy+1)*10 + (xx+1))*96 + tx];
      float gate = 1.f/(1.f + expf(-acc));
      int l = (yt*8+yy)*NWW + xt*8+xx;
      int pos = inv[b*NL + l];
      us[((size_t)(b*NL + pos))*NH + ch] = center*gate;
    }
  }
}

// decay helper: a[n] = exp(dlt*An[n]); pw path: binary powers of r (depth 5, not 15).
__device__ __forceinline__ void decay16(bool pw, float dlt, const float* An, float* a){
  if (pw){
    float r  = __expf(dlt*An[0]);
    float r2 = r*r;
    float r3 = r2*r;
    float r4 = r2*r2;
    float r8 = r4*r4;
    float r12 = r8*r4;
    a[0]=r;     a[1]=r2;     a[2]=r3;     a[3]=r4;
    a[4]=r4*r;  a[5]=r4*r2;  a[6]=r4*r3;  a[7]=r8;
    a[8]=r8*r;  a[9]=r8*r2;  a[10]=r8*r3; a[11]=r12;
    a[12]=r12*r; a[13]=r12*r2; a[14]=r12*r3; a[15]=r8*r8;
  } else {
    #pragma unroll
    for (int n = 0; n < NS; ++n) a[n] = __expf(dlt*An[n]);
  }
}
__device__ __forceinline__ bool pwcheck(const float* An){
  bool pw = true;
  #pragma unroll
  for (int n = 1; n < NS; ++n)
    pw = pw && (fabsf(An[n] - (n+1)*An[0]) <= 1e-4f*fabsf(An[n]));
  return pw;
}

// scan phase 1: per (b,chunk,d): sds = sum(dlt), Boff[n] = local scan end.
// EXACT round-0 inner loop (depth-1 prefetch, gi += NH) — hand prefetch regressed
// twice (R3/R5: VGPR 44->92, occupancy 22->14%, 90->146us). Do not touch.
__global__ __launch_bounds__(384) void k_scan1(const float* __restrict__ delta,
    const float* __restrict__ us, const float* __restrict__ Bsb,
    const float* __restrict__ A_logs, float* __restrict__ sds, float* __restrict__ Boff){
  int bc = blockIdx.x;
  int c = bc & (NCHUNKS-1);
  int b = bc >> 5;
  int d = threadIdx.x;
  __shared__ float4 Bsh[CHUNKLEN*4];
  int base = b*NL + c*CHUNKLEN;
  {
    const float4* Bg = (const float4*)(Bsb + (size_t)base*NS);
    for (int p = d; p < CHUNKLEN*4; p += 384) Bsh[p] = Bg[p];
  }
  float An[NS];
  #pragma unroll
  for (int n = 0; n < NS; ++n) An[n] = -expf(A_logs[d*NS + n]);
  bool pw = pwcheck(An);
  float h[NS];
  #pragma unroll
  for (int n = 0; n < NS; ++n) h[n]=0.f;
  float sd = 0.f;
  __syncthreads();
  size_t gi = (size_t)base*NH + d;
  float dlt = delta[gi];
  float uv  = us[gi];
  #pragma unroll 2
  for (int s = 0; s < CHUNKLEN; ++s){
    float dltc = dlt, uvc = uv;
    if (s < CHUNKLEN-1){            // prefetch next step
      dlt = delta[gi + NH];
      uv  = us[gi + NH];
    }
    float du = dltc*uvc;
    sd += dltc;
    float a[NS];
    decay16(pw, dltc, An, a);
    float bb[NS];
    #pragma unroll
    for (int q = 0; q < 4; ++q) *(float4*)&bb[4*q] = Bsh[s*4 + q];
    #pragma unroll
    for (int n = 0; n < NS; ++n) h[n] = a[n]*h[n] + du*bb[n];
    gi += NH;
  }
  // store only sum(dlt); scan2 recomputes decay exp(An*sd) on the fly (exact identity)
  sds[(size_t)bc*NH + d] = sd;
  size_t o = ((size_t)bc*NH + d)*NS;
  *(float4*)(Boff + o)      = make_float4(h[0], h[1], h[2], h[3]);
  *(float4*)(Boff + o + 4)  = make_float4(h[4], h[5], h[6], h[7]);
  *(float4*)(Boff + o + 8)  = make_float4(h[8], h[9], h[10],h[11]);
  *(float4*)(Boff + o + 12) = make_float4(h[12],h[13],h[14],h[15]);
}

// scan phase 2: compose chunk summaries; hinit written IN PLACE into Boff.
// Decay recomputed from sds + A_logs (saves 12.6MB Aprod write + read).
__global__ __launch_bounds__(256) void k_scan2(const float* __restrict__ A_logs,
    const float* __restrict__ sds, float* __restrict__ Boff){
  int i = blockIdx.x*256 + threadIdx.x;
  int dn = i % (NH*NS);
  int b = i / (NH*NS);
  float An = -expf(A_logs[dn]);   // dn = d*NS + n, matches A_logs layout
  int d = dn >> 4;
  float h = 0.f;
  for (int c = 0; c < NCHUNKS; ++c){
    int bc = b*NCHUNKS + c;
    float sd = sds[(size_t)bc*NH + d];
    float a = __expf(sd*An);
    size_t o = (size_t)bc*(NH*NS) + dn;
    float bo = Boff[o];
    Boff[o] = h;
    h = a*h + bo;
  }
}

// scan phase 3 (hinit = Boff after k_scan2).
// EXACT round-0 inner loop + tree-reduced y dot (R2-verified).
// LN stats from LDS ybuf (y captured as computed — no global re-read).
__global__ __launch_bounds__(384) void k_scan3(const float* __restrict__ delta,
    const float* __restrict__ Bsb, const float* __restrict__ Csb,
    const float* __restrict__ A_logs, const float* __restrict__ Ds,
    const float* __restrict__ hinit, float* __restrict__ us,
    float* __restrict__ lnmean, float* __restrict__ lnrstd){
  int bc = blockIdx.x;
  int c = bc & (NCHUNKS-1);
  int b = bc >> 5;
  int d = threadIdx.x;
  __shared__ float4 Bsh[CHUNKLEN*4];
  __shared__ float4 Csh[CHUNKLEN*4];
  __shared__ float ybuf[32*384];   // 48KB; total LDS 64KB -> 2 blocks/CU (grid-capped anyway)
  int base = b*NL + c*CHUNKLEN;
  {
    const float4* Bg = (const float4*)(Bsb + (size_t)base*NS);
    const float4* Cg = (const float4*)(Csb + (size_t)base*NS);
    for (int p = d; p < CHUNKLEN*4; p += 384){
      Bsh[p] = Bg[p];
      Csh[p] = Cg[p];
    }
  }
  float An[NS];
  #pragma unroll
  for (int n = 0; n < NS; ++n) An[n] = -expf(A_logs[d*NS + n]);
  bool pw = pwcheck(An);
  float h[NS];
  size_t ho = ((size_t)bc*NH + d)*NS;
  {
    float4 h0 = *(const float4*)(hinit + ho);
    float4 h1 = *(const float4*)(hinit + ho + 4);
    float4 h2 = *(const float4*)(hinit + ho + 8);
    float4 h3 = *(const float4*)(hinit + ho + 12);
    h[0]=h0.x; h[1]=h0.y; h[2]=h0.z; h[3]=h0.w;
    h[4]=h1.x; h[5]=h1.y; h[6]=h1.z; h[7]=h1.w;
    h[8]=h2.x; h[9]=h2.y; h[10]=h2.z; h[11]=h2.w;
    h[12]=h3.x; h[13]=h3.y; h[14]=h3.z; h[15]=h3.w;
  }
  float Dd = Ds[d];
  int wv = d >> 6, lane = d & 63;
  __syncthreads();
  size_t gi = (size_t)base*NH + d;
  float dlt = delta[gi];
  float uv  = us[gi];
  #pragma unroll 2
  for (int s = 0; s < CHUNKLEN; ++s){
    float dltc = dlt, uvc = uv;
    if (s < CHUNKLEN-1){            // prefetch next step
      dlt = delta[gi + NH];
      uv  = us[gi + NH];
    }
    float du = dltc*uvc;
    float a[NS];
    decay16(pw, dltc, An, a);
    float bb[NS], cc[NS];
    #pragma unroll
    for (int q = 0; q < 4; ++q){
      *(float4*)&bb[4*q] = Bsh[s*4 + q];
      *(float4*)&cc[4*q] = Csh[s*4 + q];
    }
    #pragma unroll
    for (int n = 0; n < NS; ++n) h[n] = a[n]*h[n] + du*bb[n];
    // tree-reduced dot: 4 chains of 4 FMAs instead of one 16-deep serial chain
    float ya = 0.f, yb = 0.f, yc = 0.f, yd = 0.f;
    #pragma unroll
    for (int q = 0; q < 4; ++q){
      ya += h[q]*cc[q];
      yb += h[4+q]*cc[4+q];
      yc += h[8+q]*cc[8+q];
      yd += h[12+q]*cc[12+q];
    }
    float y = ((ya+yb)+(yc+yd)) + uvc*Dd;
    us[gi] = y;
    ybuf[(s & 31)*384 + d] = y;     // capture for LN stats (same value as stored)
    gi += NH;
    if ((s & 31) == 31){            // window done: stats for 32 tokens from LDS
      __syncthreads();
      int ws0 = s - 31;
      for (int t = wv; t < 32; t += 6){
        const float* rp = &ybuf[t*384];
        float v[6];
        #pragma unroll
        for (int i = 0; i < 6; ++i) v[i] = rp[i*64 + lane];
        float sm = 0.f;
        #pragma unroll
        for (int i = 0; i < 6; ++i) sm += v[i];
        #pragma unroll
        for (int off = 32; off > 0; off >>= 1) sm += __shfl_xor(sm, off);
        float mu = sm * (1.f/NH);
        float vs = 0.f;
        #pragma unroll
        for (int i = 0; i < 6; ++i){ float dv = v[i]-mu; vs += dv*dv; }
        #pragma unroll
        for (int off = 32; off > 0; off >>= 1) vs += __shfl_xor(vs, off);
        float rs = rsqrtf(vs*(1.f/NH) + 1e-5f);
        if (lane == 0){ lnmean[base+ws0+t] = mu; lnrstd[base+ws0+t] = rs; }
      }
      __syncthreads();
    }
  }
}

extern "C" void kernel_launch(void* const* d_in, const int* in_sizes, int n_in,
                              void* d_out, int out_size, void* d_ws, size_t ws_size,
                              hipStream_t stream){
  const float* x      = (const float*)d_in[0];
  const float* tw     = (const float*)d_in[1];
  const float* gumbel = (const float*)d_in[2];
  const float* embB   = (const float*)d_in[3];
  const float* rw1    = (const float*)d_in[4];
  const float* rb1    = (const float*)d_in[5];
  const float* rw2    = (const float*)d_in[6];
  const float* rb2    = (const float*)d_in[7];
  const float* inw    = (const float*)d_in[8];
  const float* inb    = (const float*)d_in[9];
  const float* cw     = (const float*)d_in[10];
  const float* cb     = (const float*)d_in[11];
  const float* xpw    = (const float*)d_in[12];
  const float* dtw    = (const float*)d_in[13];
  const float* dtb    = (const float*)d_in[14];
  const float* A_logs = (const float*)d_in[15];
  const float* Ds     = (const float*)d_in[16];
  const float* ng     = (const float*)d_in[17];
  const float* nbv    = (const float*)d_in[18];
  const float* ow     = (const float*)d_in[19];
  const float* ob     = (const float*)d_in[20];
  const int*   gt     = (const int*)d_in[23];
  float* out = (float*)d_out;

  // Workspace layout — round-6/7/8 shape (known-good; hmid slot retained-unused;
  // dtsb eliminated by the xdd fusion, so Bof is no longer aliased by anything).
  float* ws = (float*)d_ws;
  size_t o = 0;
  float* fe   = ws + o; o += 512;
  int* idx    = (int*)(ws + o); o += NTOK;   // dead after k_xdd -> reused as LN mean
  int* rmap   = (int*)(ws + o); o += NTOK;
  int* inv    = (int*)(ws + o); o += NTOK;   // dead after k_cpe -> reused as LN rstd
  float* hmid = ws + o; o += (size_t)NTOK*64;   // unused (argmax fused into k_pre)
  float* xi   = ws + o; o += (size_t)NTOK*NH;   // reused as delta
  float* us   = ws + o; o += (size_t)NTOK*NH;   // u -> y (stays pre-LN; LN fused in out_proj)
  float* Bsb  = ws + o; o += (size_t)NTOK*NS;
  float* Csb  = ws + o; o += (size_t)NTOK*NS;
  float* sds  = ws + o; o += (size_t)NB*NCHUNKS*NH;     // per-chunk sum(dlt), 0.8 MB
  float* Bof  = ws + o; o += (size_t)NB*NCHUNKS*NH*NS;  // becomes hinit in-place via k_scan2
  short* inwb = (short*)(ws + o); o += (NH*ND)/2;
  short* owb  = (short*)(ws + o); o += (ND*NH)/2;
  short* xpwb = (short*)(ws + o); o += (56*NH)/2 + 32;
  short* dtwb = (short*)(ws + o); o += (NH*32)/2;
  float* delta = xi;
  float* lnmean = (float*)idx; // NTOK floats, idx dead by LN time (last read: k_xdd)
  float* lnrstd = (float*)inv; // NTOK floats, inv dead by LN time (last read: k_cpe)
  (void)hmid;

  // weights->bf16 + full_emb (blocks 0..63) and routing MLP+argmax (blocks 64..1087)
  k_pre<<<64 + NTOK/64,256,0,stream>>>(inw, ow, xpw, dtw, inwb, owb, xpwb, dtwb,
      embB, tw, fe, x, rw1, rb1, rw2, rb2, gumbel, idx);
  k_sort<<<NB,256,0,stream>>>(idx, rmap, inv);
  // in_proj: xi = x @ inw^T + inb (bf16 MFMA, fp32 A converted in staging)
  k_mfma<0,1,0><<<dim3(NTOK/128,6),256,0,stream>>>(x, ND, inwb, ND, inb, xi, NH, NH, ND,
      nullptr, nullptr, nullptr, nullptr, nullptr);
  // CPE gate + scatter to sorted order (div-free block: (96,4))
  k_cpe<<<NB*64*4,dim3(96,4),0,stream>>>(xi, cw, cb, inv, us);
  // x_dbl GEMM + B/C split + delta-GEMM, all fused (bit-identical to prior 3 kernels)
  k_xdd<<<NTOK/128,256,0,stream>>>(us, xpwb, dtwb, dtb, idx, fe, gt, Bsb, Csb, delta);
  // chunked scan: 32 chunks x 128 steps (round-0 structure, LDS-staged B/C)
  k_scan1<<<NB*NCHUNKS,384,0,stream>>>(delta, us, Bsb, A_logs, sds, Bof);
  k_scan2<<<(NB*NH*NS)/256,256,0,stream>>>(A_logs, sds, Bof);
  // scan3 with in-LDS LN-stats (no global re-read)
  k_scan3<<<NB*NCHUNKS,384,0,stream>>>(delta, Bsb, Csb, A_logs, Ds, Bof, us,
                                       lnmean, lnrstd);
  // out_proj (+fused LN) + scatter back to original token order
  k_mfma<3,1,1><<<dim3(NTOK/128,3),256,0,stream>>>(us, NH, owb, NH, ob, out, ND, ND, NH,
      rmap, lnmean, lnrstd, ng, nbv);
}

// Round 10
// 667.454 us; speedup vs baseline: 1.0418x; 1.0418x over previous
//
#include <hip/hip_runtime.h>
#include <math.h>

#define NB 16
#define NL 4096
#define ND 192
#define NH 384
#define NS 16
#define NTK 17
#define NIR 128
#define NR 24
#define NHH 64
#define NWW 64
#define NCHUNKS 32
#define CHUNKLEN 128
#define NTOK (NB*NL)

typedef __attribute__((ext_vector_type(8))) short short8;
typedef __attribute__((ext_vector_type(4))) float floatx4;

__device__ __forceinline__ float gelu_tanh(float x){
  return 0.5f*x*(1.0f + tanhf(0.7978845608028654f*(x + 0.044715f*x*x*x)));
}
__device__ __forceinline__ float softplus_f(float x){
  return (x > 20.0f) ? x : log1pf(expf(x));
}
__device__ __forceinline__ short f2bf(float f){
  unsigned u = __float_as_uint(f);
  unsigned r = (u + 0x7fffu + ((u >> 16) & 1u)) >> 16;
  return (short)r;
}

union Pack8 { uint4 v; short s[8]; };

// Merged pre-pass: blocks 0..63 = weights->bf16 (+ full_emb on block 0);
// blocks 64..1087 = routing MLP + argmax (independent work, one launch saved).
__global__ __launch_bounds__(256) void k_pre(
    const float* __restrict__ inw, const float* __restrict__ ow,
    const float* __restrict__ xpw, const float* __restrict__ dtw,
    short* __restrict__ inwb, short* __restrict__ owb,
    short* __restrict__ xpwb, short* __restrict__ dtwb,
    const float* __restrict__ embB, const float* __restrict__ tw,
    float* __restrict__ fe,
    const float* __restrict__ x, const float* __restrict__ rw1,
    const float* __restrict__ rb1, const float* __restrict__ rw2,
    const float* __restrict__ rb2, const float* __restrict__ gumbel,
    int* __restrict__ idx){
  __shared__ float As[16][68];
  __shared__ float Ws[16][68];
  __shared__ float hm[64*65];
  __shared__ float w2s[NTK*64];
  int tid = threadIdx.x;
  int bl = blockIdx.x;
  if (bl < 64){
    // ---- weight conversion path (stride = 64 blocks, as in old k_cvtw) ----
    int i = bl*256 + tid;
    int stride = 64*256;
    for (int p = i; p < NH*ND; p += stride) inwb[p] = f2bf(inw[p]);
    for (int p = i; p < ND*NH; p += stride) owb[p] = f2bf(ow[p]);
    for (int p = i; p < 56*NH; p += stride) xpwb[p] = f2bf(xpw[p]);
    for (int p = i; p < NH*32; p += stride){
      int r = p >> 5, c = p & 31;
      dtwb[p] = (c < NR) ? f2bf(dtw[r*NR + c]) : (short)0;
    }
    if (bl == 0){
      for (int o = tid; o < NTK*NS; o += 256){
        int t = o / NS, s = o % NS;
        float acc = 0.f;
        for (int k = 0; k < NIR; ++k) acc += embB[t*NIR+k]*tw[k*NS+s];
        fe[o] = acc;
      }
    }
    return;
  }
  // ---- routing path: hmid = gelu(x@rw1^T+rb1); idx = argmax(...) ----
  int m0 = (bl - 64)*64;
  int tx = tid & 15, ty = tid >> 4;
  int srow = tid >> 2, skseg = (tid & 3)*4;
  for (int p = tid; p < NTK*64; p += 256) w2s[p] = rw2[p];
  float acc[4][4] = {};
  for (int k0 = 0; k0 < ND; k0 += 16){
    {
      const float* ap = x + (size_t)(m0+srow)*ND + k0 + skseg;
      float4 v = *(const float4*)ap;
      As[skseg+0][srow]=v.x; As[skseg+1][srow]=v.y;
      As[skseg+2][srow]=v.z; As[skseg+3][srow]=v.w;
    }
    {
      float4 v = *(const float4*)(rw1 + (size_t)srow*ND + k0 + skseg);
      Ws[skseg+0][srow]=v.x; Ws[skseg+1][srow]=v.y;
      Ws[skseg+2][srow]=v.z; Ws[skseg+3][srow]=v.w;
    }
    __syncthreads();
    #pragma unroll
    for (int kk = 0; kk < 16; ++kk){
      float4 av = *(const float4*)&As[kk][ty*4];
      float4 wv = *(const float4*)&Ws[kk][tx*4];
      acc[0][0] += av.x*wv.x; acc[0][1] += av.x*wv.y;
      acc[0][2] += av.x*wv.z; acc[0][3] += av.x*wv.w;
      acc[1][0] += av.y*wv.x; acc[1][1] += av.y*wv.y;
      acc[1][2] += av.y*wv.z; acc[1][3] += av.y*wv.w;
      acc[2][0] += av.z*wv.x; acc[2][1] += av.z*wv.y;
      acc[2][2] += av.z*wv.z; acc[2][3] += av.z*wv.w;
      acc[3][0] += av.w*wv.x; acc[3][1] += av.w*wv.y;
      acc[3][2] += av.w*wv.z; acc[3][3] += av.w*wv.w;
    }
    __syncthreads();
  }
  #pragma unroll
  for (int i = 0; i < 4; ++i)
    #pragma unroll
    for (int j = 0; j < 4; ++j)
      hm[(ty*4+i)*65 + tx*4+j] = gelu_tanh(acc[i][j] + rb1[tx*4+j]);
  __syncthreads();
  if (tid < 64){
    int g = m0 + tid;
    const float* hr = &hm[tid*65];
    float best = -INFINITY; int bi = 0;
    for (int c = 0; c < NTK; ++c){
      float s = rb2[c] + gumbel[(size_t)g*NTK + c];
      #pragma unroll
      for (int j = 0; j < 64; ++j) s += hr[j]*w2s[c*64+j];
      if (s > best){ best = s; bi = c; }
    }
    idx[g] = bi;
  }
}

// bf16 MFMA GEMM: C(MxN) = A(MxK) @ W(NxK bf16)^T + bias.
// A fp32 (AF32=1, converted during LDS staging) or bf16 (AF32=0).
// LNA=1: apply per-row layernorm (mean/rstd precomputed; g/b over K) during staging.
// EPI: 0 none, 2 softplus, 3 row-scatter via remap
template<int EPI, int AF32, int LNA>
__global__ __launch_bounds__(256) void k_mfma(const void* __restrict__ Aptr, int lda,
    const short* __restrict__ Wbf, int ldw, const float* __restrict__ bias,
    float* __restrict__ C, int ldc, int N, int K, const int* __restrict__ remap,
    const float* __restrict__ lnm, const float* __restrict__ lnr,
    const float* __restrict__ lng, const float* __restrict__ lnb){
  __shared__ short As[128*40];   // stride 40 shorts = 80B: 16B-aligned b128, 2-way banks (free)
  __shared__ short Bs[64*40];
  int tid = threadIdx.x;
  int m0 = blockIdx.x*128, n0 = blockIdx.y*64;
  int w = tid >> 6, lane = tid & 63;
  int lq = lane >> 4, lr = lane & 15;
  floatx4 acc[2][4];
  #pragma unroll
  for (int i = 0; i < 2; ++i)
    #pragma unroll
    for (int j = 0; j < 4; ++j) acc[i][j] = (floatx4){0.f,0.f,0.f,0.f};
  int ar = tid >> 1, aq = (tid & 1)*2;   // A: each thread stages 16 elts of one row
  int br = tid >> 2, bq = tid & 3;       // B: each thread stages 8 elts of one row
  float mr = 0.f, rr = 0.f;
  if (LNA){ mr = lnm[m0+ar]; rr = lnr[m0+ar]; }
  for (int k0 = 0; k0 < K; k0 += 32){
    Pack8 sa0, sa1;
    if (AF32){
      const float* ap = (const float*)Aptr + (size_t)(m0+ar)*lda + k0 + aq*8;
      float f[16];
      float4 f0 = *(const float4*)(ap);
      float4 f1 = *(const float4*)(ap+4);
      float4 f2 = *(const float4*)(ap+8);
      float4 f3 = *(const float4*)(ap+12);
      f[0]=f0.x; f[1]=f0.y; f[2]=f0.z; f[3]=f0.w;
      f[4]=f1.x; f[5]=f1.y; f[6]=f1.z; f[7]=f1.w;
      f[8]=f2.x; f[9]=f2.y; f[10]=f2.z; f[11]=f2.w;
      f[12]=f3.x; f[13]=f3.y; f[14]=f3.z; f[15]=f3.w;
      if (LNA){
        const float* gp = lng + k0 + aq*8;
        const float* bp = lnb + k0 + aq*8;
        #pragma unroll
        for (int j = 0; j < 16; ++j) f[j] = (f[j]-mr)*rr*gp[j] + bp[j];
      }
      #pragma unroll
      for (int j = 0; j < 8; ++j){ sa0.s[j] = f2bf(f[j]); sa1.s[j] = f2bf(f[8+j]); }
    } else {
      const short* ap = (const short*)Aptr + (size_t)(m0+ar)*lda + k0 + aq*8;
      sa0.v = *(const uint4*)ap;
      sa1.v = *(const uint4*)(ap + 8);
    }
    uint4 bv = {0u,0u,0u,0u};
    if (n0 + br < N) bv = *(const uint4*)(Wbf + (size_t)(n0+br)*ldw + k0 + bq*8);
    __syncthreads();
    *(uint4*)&As[ar*40 + aq*8]     = sa0.v;
    *(uint4*)&As[ar*40 + aq*8 + 8] = sa1.v;
    *(uint4*)&Bs[br*40 + bq*8]     = bv;
    __syncthreads();
    short8 a0 = *(const short8*)&As[(w*32      + lr)*40 + lq*8];
    short8 a1 = *(const short8*)&As[(w*32 + 16 + lr)*40 + lq*8];
    short8 b0 = *(const short8*)&Bs[(     lr)*40 + lq*8];
    short8 b1 = *(const short8*)&Bs[(16 + lr)*40 + lq*8];
    short8 b2 = *(const short8*)&Bs[(32 + lr)*40 + lq*8];
    short8 b3 = *(const short8*)&Bs[(48 + lr)*40 + lq*8];
    acc[0][0] = __builtin_amdgcn_mfma_f32_16x16x32_bf16(a0, b0, acc[0][0], 0,0,0);
    acc[0][1] = __builtin_amdgcn_mfma_f32_16x16x32_bf16(a0, b1, acc[0][1], 0,0,0);
    acc[0][2] = __builtin_amdgcn_mfma_f32_16x16x32_bf16(a0, b2, acc[0][2], 0,0,0);
    acc[0][3] = __builtin_amdgcn_mfma_f32_16x16x32_bf16(a0, b3, acc[0][3], 0,0,0);
    acc[1][0] = __builtin_amdgcn_mfma_f32_16x16x32_bf16(a1, b0, acc[1][0], 0,0,0);
    acc[1][1] = __builtin_amdgcn_mfma_f32_16x16x32_bf16(a1, b1, acc[1][1], 0,0,0);
    acc[1][2] = __builtin_amdgcn_mfma_f32_16x16x32_bf16(a1, b2, acc[1][2], 0,0,0);
    acc[1][3] = __builtin_amdgcn_mfma_f32_16x16x32_bf16(a1, b3, acc[1][3], 0,0,0);
  }
  // C/D layout (verified m89): col = lane&15, row = (lane>>4)*4 + reg
  #pragma unroll
  for (int mt = 0; mt < 2; ++mt){
    #pragma unroll
    for (int r = 0; r < 4; ++r){
      int m = m0 + w*32 + mt*16 + lq*4 + r;
      int orow = (EPI==3) ? remap[m] : m;
      #pragma unroll
      for (int nt = 0; nt < 4; ++nt){
        int n = n0 + nt*16 + lr;
        if (n < N){
          float v = acc[mt][nt][r] + (bias ? bias[n] : 0.f);
          if (EPI==2) v = softplus_f(v);
          C[(size_t)orow*ldc + n] = v;
        }
      }
    }
  }
}

// x_dbl GEMM (N=56, K=384, A=us fp32) with FUSED k_bc epilogue:
// columns 0..23 -> dtsb (bf16, zero-pad 24..31), 24..39 -> Bsb, 40..55 -> Csb+prompt.
// Saves the 15MB dbl write + 15MB re-read + one launch. (R8-verified; the R9
// attempt to also fuse the delta-GEMM here regressed: 512-block serial tail +
// LDS bank conflicts on short stores -> 135us vs ~114us split. Keep split.)
__global__ __launch_bounds__(256) void k_xdbl(const float* __restrict__ us,
    const short* __restrict__ xpwb, const int* __restrict__ idx,
    const float* __restrict__ fe, const int* __restrict__ gt,
    float* __restrict__ Bsb, float* __restrict__ Csb, short* __restrict__ dtsb){
  __shared__ short As[128*40];
  __shared__ short Bs[64*40];
  int tid = threadIdx.x;
  int m0 = blockIdx.x*128;
  int w = tid >> 6, lane = tid & 63;
  int lq = lane >> 4, lr = lane & 15;
  floatx4 acc[2][4];
  #pragma unroll
  for (int i = 0; i < 2; ++i)
    #pragma unroll
    for (int j = 0; j < 4; ++j) acc[i][j] = (floatx4){0.f,0.f,0.f,0.f};
  int ar = tid >> 1, aq = (tid & 1)*2;
  int br = tid >> 2, bq = tid & 3;
  for (int k0 = 0; k0 < NH; k0 += 32){
    Pack8 sa0, sa1;
    {
      const float* ap = us + (size_t)(m0+ar)*NH + k0 + aq*8;
      float f[16];
      float4 f0 = *(const float4*)(ap);
      float4 f1 = *(const float4*)(ap+4);
      float4 f2 = *(const float4*)(ap+8);
      float4 f3 = *(const float4*)(ap+12);
      f[0]=f0.x; f[1]=f0.y; f[2]=f0.z; f[3]=f0.w;
      f[4]=f1.x; f[5]=f1.y; f[6]=f1.z; f[7]=f1.w;
      f[8]=f2.x; f[9]=f2.y; f[10]=f2.z; f[11]=f2.w;
      f[12]=f3.x; f[13]=f3.y; f[14]=f3.z; f[15]=f3.w;
      #pragma unroll
      for (int j = 0; j < 8; ++j){ sa0.s[j] = f2bf(f[j]); sa1.s[j] = f2bf(f[8+j]); }
    }
    uint4 bv = {0u,0u,0u,0u};
    if (br < 56) bv = *(const uint4*)(xpwb + (size_t)br*NH + k0 + bq*8);
    __syncthreads();
    *(uint4*)&As[ar*40 + aq*8]     = sa0.v;
    *(uint4*)&As[ar*40 + aq*8 + 8] = sa1.v;
    *(uint4*)&Bs[br*40 + bq*8]     = bv;
    __syncthreads();
    short8 a0 = *(const short8*)&As[(w*32      + lr)*40 + lq*8];
    short8 a1 = *(const short8*)&As[(w*32 + 16 + lr)*40 + lq*8];
    short8 b0 = *(const short8*)&Bs[(     lr)*40 + lq*8];
    short8 b1 = *(const short8*)&Bs[(16 + lr)*40 + lq*8];
    short8 b2 = *(const short8*)&Bs[(32 + lr)*40 + lq*8];
    short8 b3 = *(const short8*)&Bs[(48 + lr)*40 + lq*8];
    acc[0][0] = __builtin_amdgcn_mfma_f32_16x16x32_bf16(a0, b0, acc[0][0], 0,0,0);
    acc[0][1] = __builtin_amdgcn_mfma_f32_16x16x32_bf16(a0, b1, acc[0][1], 0,0,0);
    acc[0][2] = __builtin_amdgcn_mfma_f32_16x16x32_bf16(a0, b2, acc[0][2], 0,0,0);
    acc[0][3] = __builtin_amdgcn_mfma_f32_16x16x32_bf16(a0, b3, acc[0][3], 0,0,0);
    acc[1][0] = __builtin_amdgcn_mfma_f32_16x16x32_bf16(a1, b0, acc[1][0], 0,0,0);
    acc[1][1] = __builtin_amdgcn_mfma_f32_16x16x32_bf16(a1, b1, acc[1][1], 0,0,0);
    acc[1][2] = __builtin_amdgcn_mfma_f32_16x16x32_bf16(a1, b2, acc[1][2], 0,0,0);
    acc[1][3] = __builtin_amdgcn_mfma_f32_16x16x32_bf16(a1, b3, acc[1][3], 0,0,0);
  }
  int gather = gt[0];
  #pragma unroll
  for (int mt = 0; mt < 2; ++mt){
    #pragma unroll
    for (int r = 0; r < 4; ++r){
      int m = m0 + w*32 + mt*16 + lq*4 + r;
      int id = idx[m];
      #pragma unroll
      for (int nt = 0; nt < 4; ++nt){
        int n = nt*16 + lr;
        float v = acc[mt][nt][r];
        if (n < 24){
          dtsb[(size_t)m*32 + n] = f2bf(v);
        } else if (n < 40){
          Bsb[(size_t)m*NS + (n-24)] = v;
          if (n < 32) dtsb[(size_t)m*32 + n] = 0;
        } else if (n < 56){
          float cv = v;
          if (gather != 0) cv += fe[id*NS + (n-40)];
          Csb[(size_t)m*NS + (n-40)] = cv;
        }
      }
    }
  }
}

// stable counting sort per batch over 17 keys
__global__ __launch_bounds__(256) void k_sort(const int* __restrict__ idx,
    int* __restrict__ rmap, int* __restrict__ inv){
  int b = blockIdx.x, t = threadIdx.x;
  __shared__ int hist[NTK][256];
  __shared__ int tot[NTK];
  __shared__ int keybase[NTK];
  int keys[16];
  const int* ip = idx + b*NL + t*16;
  #pragma unroll
  for (int i = 0; i < 16; ++i) keys[i] = ip[i];
  #pragma unroll
  for (int k = 0; k < NTK; ++k){
    int c = 0;
    #pragma unroll
    for (int i = 0; i < 16; ++i) c += (keys[i]==k) ? 1 : 0;
    hist[k][t] = c;
  }
  __syncthreads();
  if (t < NTK){
    int run = 0;
    for (int j = 0; j < 256; ++j){ int v = hist[t][j]; hist[t][j] = run; run += v; }
    tot[t] = run;
  }
  __syncthreads();
  if (t == 0){
    int base = 0;
    for (int k = 0; k < NTK; ++k){ keybase[k] = base; base += tot[k]; }
  }
  __syncthreads();
  #pragma unroll
  for (int i = 0; i < 16; ++i){
    int k = keys[i];
    int cb = 0;
    #pragma unroll
    for (int j = 0; j < 16; ++j) cb += (j < i && keys[j]==k) ? 1 : 0;
    int pos = keybase[k] + hist[k][t] + cb;
    rmap[b*NL + pos] = b*NL + t*16 + i;
    inv[b*NL + t*16 + i] = pos;
  }
}

// depthwise 3x3 SAME conv + sigmoid gate; scatter rows to sorted order.
// Block (96,4): threadIdx.x IS the channel -> zero integer div/mod anywhere.
__global__ __launch_bounds__(384) void k_cpe(const float* __restrict__ xi,
    const float* __restrict__ cw, const float* __restrict__ cb,
    const int* __restrict__ inv, float* __restrict__ us){
  int bl = blockIdx.x;
  int cg = bl & 3;
  int xt = (bl>>2) & 7;
  int yt = (bl>>5) & 7;
  int b  = bl >> 8;
  __shared__ float tile[10*10*96];   // [yy][xx][c], c contiguous
  int tx = threadIdx.x;              // channel within group (0..95)
  int ty = threadIdx.y;              // spatial worker (0..3)
  int c0 = cg*96;
  int ch = c0 + tx;
  // stage 10x10 halo tile, c-major coalesced, no divisions
  for (int yy = 0; yy < 10; ++yy){
    int gy = yt*8 + yy - 1;
    for (int xx = ty; xx < 10; xx += 4){
      int gx = xt*8 + xx - 1;
      float v = 0.f;
      if (gy >= 0 && gy < NHH && gx >= 0 && gx < NWW)
        v = xi[((size_t)(b*NL + gy*NWW + gx))*NH + ch];
      tile[(yy*10 + xx)*96 + tx] = v;
    }
  }
  // conv weights fixed per thread: hoist to registers
  float wreg[9];
  #pragma unroll
  for (int j = 0; j < 9; ++j) wreg[j] = cw[ch*9 + j];
  float bias = cb[ch];
  __syncthreads();
  for (int yy = ty; yy < 8; yy += 4){
    #pragma unroll
    for (int xx = 0; xx < 8; ++xx){
      float acc = bias;
      #pragma unroll
      for (int dy = 0; dy < 3; ++dy)
        #pragma unroll
        for (int dx = 0; dx < 3; ++dx)
          acc += tile[((yy+dy)*10 + (xx+dx))*96 + tx] * wreg[dy*3+dx];
      float center = tile[((yy+1)*10 + (xx+1))*96 + tx];
      float gate = 1.f/(1.f + expf(-acc));
      int l = (yt*8+yy)*NWW + xt*8+xx;
      int pos = inv[b*NL + l];
      us[((size_t)(b*NL + pos))*NH + ch] = center*gate;
    }
  }
}

// decay helper: a[n] = exp(dlt*An[n]); pw path: binary powers of r (depth 5, not 15).
__device__ __forceinline__ void decay16(bool pw, float dlt, const float* An, float* a){
  if (pw){
    float r  = __expf(dlt*An[0]);
    float r2 = r*r;
    float r3 = r2*r;
    float r4 = r2*r2;
    float r8 = r4*r4;
    float r12 = r8*r4;
    a[0]=r;     a[1]=r2;     a[2]=r3;     a[3]=r4;
    a[4]=r4*r;  a[5]=r4*r2;  a[6]=r4*r3;  a[7]=r8;
    a[8]=r8*r;  a[9]=r8*r2;  a[10]=r8*r3; a[11]=r12;
    a[12]=r12*r; a[13]=r12*r2; a[14]=r12*r3; a[15]=r8*r8;
  } else {
    #pragma unroll
    for (int n = 0; n < NS; ++n) a[n] = __expf(dlt*An[n]);
  }
}
__device__ __forceinline__ bool pwcheck(const float* An){
  bool pw = true;
  #pragma unroll
  for (int n = 1; n < NS; ++n)
    pw = pw && (fabsf(An[n] - (n+1)*An[0]) <= 1e-4f*fabsf(An[n]));
  return pw;
}

// scan phase 1: per (b,chunk,d): sds = sum(dlt), Boff[n] = local scan end.
// EXACT round-0 inner loop (depth-1 prefetch, gi += NH) — hand prefetch regressed
// twice (R3/R5: VGPR 44->92, occupancy 22->14%, 90->146us). Do not touch.
__global__ __launch_bounds__(384) void k_scan1(const float* __restrict__ delta,
    const float* __restrict__ us, const float* __restrict__ Bsb,
    const float* __restrict__ A_logs, float* __restrict__ sds, float* __restrict__ Boff){
  int bc = blockIdx.x;
  int c = bc & (NCHUNKS-1);
  int b = bc >> 5;
  int d = threadIdx.x;
  __shared__ float4 Bsh[CHUNKLEN*4];
  int base = b*NL + c*CHUNKLEN;
  {
    const float4* Bg = (const float4*)(Bsb + (size_t)base*NS);
    for (int p = d; p < CHUNKLEN*4; p += 384) Bsh[p] = Bg[p];
  }
  float An[NS];
  #pragma unroll
  for (int n = 0; n < NS; ++n) An[n] = -expf(A_logs[d*NS + n]);
  bool pw = pwcheck(An);
  float h[NS];
  #pragma unroll
  for (int n = 0; n < NS; ++n) h[n]=0.f;
  float sd = 0.f;
  __syncthreads();
  size_t gi = (size_t)base*NH + d;
  float dlt = delta[gi];
  float uv  = us[gi];
  #pragma unroll 2
  for (int s = 0; s < CHUNKLEN; ++s){
    float dltc = dlt, uvc = uv;
    if (s < CHUNKLEN-1){            // prefetch next step
      dlt = delta[gi + NH];
      uv  = us[gi + NH];
    }
    float du = dltc*uvc;
    sd += dltc;
    float a[NS];
    decay16(pw, dltc, An, a);
    float bb[NS];
    #pragma unroll
    for (int q = 0; q < 4; ++q) *(float4*)&bb[4*q] = Bsh[s*4 + q];
    #pragma unroll
    for (int n = 0; n < NS; ++n) h[n] = a[n]*h[n] + du*bb[n];
    gi += NH;
  }
  // store only sum(dlt); scan2 recomputes decay exp(An*sd) on the fly (exact identity)
  sds[(size_t)bc*NH + d] = sd;
  size_t o = ((size_t)bc*NH + d)*NS;
  *(float4*)(Boff + o)      = make_float4(h[0], h[1], h[2], h[3]);
  *(float4*)(Boff + o + 4)  = make_float4(h[4], h[5], h[6], h[7]);
  *(float4*)(Boff + o + 8)  = make_float4(h[8], h[9], h[10],h[11]);
  *(float4*)(Boff + o + 12) = make_float4(h[12],h[13],h[14],h[15]);
}

// scan phase 2: compose chunk summaries; hinit written IN PLACE into Boff.
// Decay recomputed from sds + A_logs (saves 12.6MB Aprod write + read).
__global__ __launch_bounds__(256) void k_scan2(const float* __restrict__ A_logs,
    const float* __restrict__ sds, float* __restrict__ Boff){
  int i = blockIdx.x*256 + threadIdx.x;
  int dn = i % (NH*NS);
  int b = i / (NH*NS);
  float An = -expf(A_logs[dn]);   // dn = d*NS + n, matches A_logs layout
  int d = dn >> 4;
  float h = 0.f;
  for (int c = 0; c < NCHUNKS; ++c){
    int bc = b*NCHUNKS + c;
    float sd = sds[(size_t)bc*NH + d];
    float a = __expf(sd*An);
    size_t o = (size_t)bc*(NH*NS) + dn;
    float bo = Boff[o];
    Boff[o] = h;
    h = a*h + bo;
  }
}

// scan phase 3 (hinit = Boff after k_scan2).
// EXACT round-0 inner loop + tree-reduced y dot (R2-verified).
// LN stats from LDS ybuf (y captured as computed — no global re-read).
__global__ __launch_bounds__(384) void k_scan3(const float* __restrict__ delta,
    const float* __restrict__ Bsb, const float* __restrict__ Csb,
    const float* __restrict__ A_logs, const float* __restrict__ Ds,
    const float* __restrict__ hinit, float* __restrict__ us,
    float* __restrict__ lnmean, float* __restrict__ lnrstd){
  int bc = blockIdx.x;
  int c = bc & (NCHUNKS-1);
  int b = bc >> 5;
  int d = threadIdx.x;
  __shared__ float4 Bsh[CHUNKLEN*4];
  __shared__ float4 Csh[CHUNKLEN*4];
  __shared__ float ybuf[32*384];   // 48KB; total LDS 64KB -> 2 blocks/CU (grid-capped anyway)
  int base = b*NL + c*CHUNKLEN;
  {
    const float4* Bg = (const float4*)(Bsb + (size_t)base*NS);
    const float4* Cg = (const float4*)(Csb + (size_t)base*NS);
    for (int p = d; p < CHUNKLEN*4; p += 384){
      Bsh[p] = Bg[p];
      Csh[p] = Cg[p];
    }
  }
  float An[NS];
  #pragma unroll
  for (int n = 0; n < NS; ++n) An[n] = -expf(A_logs[d*NS + n]);
  bool pw = pwcheck(An);
  float h[NS];
  size_t ho = ((size_t)bc*NH + d)*NS;
  {
    float4 h0 = *(const float4*)(hinit + ho);
    float4 h1 = *(const float4*)(hinit + ho + 4);
    float4 h2 = *(const float4*)(hinit + ho + 8);
    float4 h3 = *(const float4*)(hinit + ho + 12);
    h[0]=h0.x; h[1]=h0.y; h[2]=h0.z; h[3]=h0.w;
    h[4]=h1.x; h[5]=h1.y; h[6]=h1.z; h[7]=h1.w;
    h[8]=h2.x; h[9]=h2.y; h[10]=h2.z; h[11]=h2.w;
    h[12]=h3.x; h[13]=h3.y; h[14]=h3.z; h[15]=h3.w;
  }
  float Dd = Ds[d];
  int wv = d >> 6, lane = d & 63;
  __syncthreads();
  size_t gi = (size_t)base*NH + d;
  float dlt = delta[gi];
  float uv  = us[gi];
  #pragma unroll 2
  for (int s = 0; s < CHUNKLEN; ++s){
    float dltc = dlt, uvc = uv;
    if (s < CHUNKLEN-1){            // prefetch next step
      dlt = delta[gi + NH];
      uv  = us[gi + NH];
    }
    float du = dltc*uvc;
    float a[NS];
    decay16(pw, dltc, An, a);
    float bb[NS], cc[NS];
    #pragma unroll
    for (int q = 0; q < 4; ++q){
      *(float4*)&bb[4*q] = Bsh[s*4 + q];
      *(float4*)&cc[4*q] = Csh[s*4 + q];
    }
    #pragma unroll
    for (int n = 0; n < NS; ++n) h[n] = a[n]*h[n] + du*bb[n];
    // tree-reduced dot: 4 chains of 4 FMAs instead of one 16-deep serial chain
    float ya = 0.f, yb = 0.f, yc = 0.f, yd = 0.f;
    #pragma unroll
    for (int q = 0; q < 4; ++q){
      ya += h[q]*cc[q];
      yb += h[4+q]*cc[4+q];
      yc += h[8+q]*cc[8+q];
      yd += h[12+q]*cc[12+q];
    }
    float y = ((ya+yb)+(yc+yd)) + uvc*Dd;
    us[gi] = y;
    ybuf[(s & 31)*384 + d] = y;     // capture for LN stats (same value as stored)
    gi += NH;
    if ((s & 31) == 31){            // window done: stats for 32 tokens from LDS
      __syncthreads();
      int ws0 = s - 31;
      for (int t = wv; t < 32; t += 6){
        const float* rp = &ybuf[t*384];
        float v[6];
        #pragma unroll
        for (int i = 0; i < 6; ++i) v[i] = rp[i*64 + lane];
        float sm = 0.f;
        #pragma unroll
        for (int i = 0; i < 6; ++i) sm += v[i];
        #pragma unroll
        for (int off = 32; off > 0; off >>= 1) sm += __shfl_xor(sm, off);
        float mu = sm * (1.f/NH);
        float vs = 0.f;
        #pragma unroll
        for (int i = 0; i < 6; ++i){ float dv = v[i]-mu; vs += dv*dv; }
        #pragma unroll
        for (int off = 32; off > 0; off >>= 1) vs += __shfl_xor(vs, off);
        float rs = rsqrtf(vs*(1.f/NH) + 1e-5f);
        if (lane == 0){ lnmean[base+ws0+t] = mu; lnrstd[base+ws0+t] = rs; }
      }
      __syncthreads();
    }
  }
}

extern "C" void kernel_launch(void* const* d_in, const int* in_sizes, int n_in,
                              void* d_out, int out_size, void* d_ws, size_t ws_size,
                              hipStream_t stream){
  const float* x      = (const float*)d_in[0];
  const float* tw     = (const float*)d_in[1];
  const float* gumbel = (const float*)d_in[2];
  const float* embB   = (const float*)d_in[3];
  const float* rw1    = (const float*)d_in[4];
  const float* rb1    = (const float*)d_in[5];
  const float* rw2    = (const float*)d_in[6];
  const float* rb2    = (const float*)d_in[7];
  const float* inw    = (const float*)d_in[8];
  const float* inb    = (const float*)d_in[9];
  const float* cw     = (const float*)d_in[10];
  const float* cb     = (const float*)d_in[11];
  const float* xpw    = (const float*)d_in[12];
  const float* dtw    = (const float*)d_in[13];
  const float* dtb    = (const float*)d_in[14];
  const float* A_logs = (const float*)d_in[15];
  const float* Ds     = (const float*)d_in[16];
  const float* ng     = (const float*)d_in[17];
  const float* nbv    = (const float*)d_in[18];
  const float* ow     = (const float*)d_in[19];
  const float* ob     = (const float*)d_in[20];
  const int*   gt     = (const int*)d_in[23];
  float* out = (float*)d_out;

  // Workspace layout — round-8 shape (known-good; hmid slot retained-unused;
  // dtsb aliases Bof, disjoint lifetime: dtsb dies at delta-GEMM, Bof written by scan1).
  float* ws = (float*)d_ws;
  size_t o = 0;
  float* fe   = ws + o; o += 512;
  int* idx    = (int*)(ws + o); o += NTOK;   // dead after k_xdbl -> reused as LN mean
  int* rmap   = (int*)(ws + o); o += NTOK;
  int* inv    = (int*)(ws + o); o += NTOK;   // dead after k_cpe -> reused as LN rstd
  float* hmid = ws + o; o += (size_t)NTOK*64;   // unused (argmax fused into k_pre)
  float* xi   = ws + o; o += (size_t)NTOK*NH;   // reused as delta
  float* us   = ws + o; o += (size_t)NTOK*NH;   // u -> y (stays pre-LN; LN fused in out_proj)
  float* Bsb  = ws + o; o += (size_t)NTOK*NS;
  float* Csb  = ws + o; o += (size_t)NTOK*NS;
  float* sds  = ws + o; o += (size_t)NB*NCHUNKS*NH;     // per-chunk sum(dlt), 0.8 MB
  float* Bof  = ws + o; o += (size_t)NB*NCHUNKS*NH*NS;  // becomes hinit in-place via k_scan2
  short* inwb = (short*)(ws + o); o += (NH*ND)/2;
  short* owb  = (short*)(ws + o); o += (ND*NH)/2;
  short* xpwb = (short*)(ws + o); o += (56*NH)/2 + 32;
  short* dtwb = (short*)(ws + o); o += (NH*32)/2;
  float* delta = xi;
  short* dtsb = (short*)Bof;   // NTOK*32 shorts = 4 MB, dies before k_scan1 writes Bof
  float* lnmean = (float*)idx; // NTOK floats, idx dead by LN time (last read: k_xdbl)
  float* lnrstd = (float*)inv; // NTOK floats, inv dead by LN time (last read: k_cpe)
  (void)hmid;

  // weights->bf16 + full_emb (blocks 0..63) and routing MLP+argmax (blocks 64..1087)
  k_pre<<<64 + NTOK/64,256,0,stream>>>(inw, ow, xpw, dtw, inwb, owb, xpwb, dtwb,
      embB, tw, fe, x, rw1, rb1, rw2, rb2, gumbel, idx);
  k_sort<<<NB,256,0,stream>>>(idx, rmap, inv);
  // in_proj: xi = x @ inw^T + inb (bf16 MFMA, fp32 A converted in staging)
  k_mfma<0,1,0><<<dim3(NTOK/128,6),256,0,stream>>>(x, ND, inwb, ND, inb, xi, NH, NH, ND,
      nullptr, nullptr, nullptr, nullptr, nullptr);
  // CPE gate + scatter to sorted order (div-free block: (96,4))
  k_cpe<<<NB*64*4,dim3(96,4),0,stream>>>(xi, cw, cb, inv, us);
  // x_dbl GEMM with fused B/C/dts split epilogue (R8 champion structure)
  k_xdbl<<<NTOK/128,256,0,stream>>>(us, xpwb, idx, fe, gt, Bsb, Csb, dtsb);
  // delta = softplus(dts @ dtw^T + dtb)  (bf16 MFMA, K=32 padded; high-TLP standalone)
  k_mfma<2,0,0><<<dim3(NTOK/128,6),256,0,stream>>>(dtsb, 32, dtwb, 32, dtb, delta, NH, NH, 32,
      nullptr, nullptr, nullptr, nullptr, nullptr);
  // chunked scan: 32 chunks x 128 steps (round-0 structure, LDS-staged B/C)
  k_scan1<<<NB*NCHUNKS,384,0,stream>>>(delta, us, Bsb, A_logs, sds, Bof);
  k_scan2<<<(NB*NH*NS)/256,256,0,stream>>>(A_logs, sds, Bof);
  // scan3 with in-LDS LN-stats (no global re-read)
  k_scan3<<<NB*NCHUNKS,384,0,stream>>>(delta, Bsb, Csb, A_logs, Ds, Bof, us,
                                       lnmean, lnrstd);
  // out_proj (+fused LN) + scatter back to original token order
  k_mfma<3,1,1><<<dim3(NTOK/128,3),256,0,stream>>>(us, NH, owb, NH, ob, out, ND, ND, NH,
      rmap, lnmean, lnrstd, ng, nbv);
}